// Round 5
// baseline (216.563 us; speedup 1.0000x reference)
//
#include <hip/hip_runtime.h>
#include <hip/hip_bf16.h>

#define N_NODES 100000
#define N_EDGES 1250000
#define D_FEAT  64
#define E4      (N_EDGES / 4)        // 312500 exactly
#define MAXDEG  32                   // P(Poisson(12.5) > 32) ~ 1.7e-6/node; overflow handled
#define OVF_CAP 16384

// Fused phase 1: histogram + direct slot scatter. 4 edges/thread.
// slots[d*MAXDEG + r] = src. Rare overflow -> side list for post-gather fixup.
__global__ __launch_bounds__(256) void histo_scatter4(
    const int* __restrict__ src, const int* __restrict__ dst,
    int* __restrict__ count, int* __restrict__ slots,
    int* __restrict__ ovfCnt, int2* __restrict__ ovf)
{
    int e4 = blockIdx.x * blockDim.x + threadIdx.x;
    if (e4 >= E4) return;
    int4 d = ((const int4*)dst)[e4];
    int4 s = ((const int4*)src)[e4];

    int r0 = atomicAdd(&count[d.x], 1);
    int r1 = atomicAdd(&count[d.y], 1);
    int r2 = atomicAdd(&count[d.z], 1);
    int r3 = atomicAdd(&count[d.w], 1);

    if (r0 < MAXDEG) slots[d.x * MAXDEG + r0] = s.x;
    else { int o = atomicAdd(ovfCnt, 1); if (o < OVF_CAP) ovf[o] = make_int2(s.x, d.x); }
    if (r1 < MAXDEG) slots[d.y * MAXDEG + r1] = s.y;
    else { int o = atomicAdd(ovfCnt, 1); if (o < OVF_CAP) ovf[o] = make_int2(s.y, d.y); }
    if (r2 < MAXDEG) slots[d.z * MAXDEG + r2] = s.z;
    else { int o = atomicAdd(ovfCnt, 1); if (o < OVF_CAP) ovf[o] = make_int2(s.z, d.z); }
    if (r3 < MAXDEG) slots[d.w * MAXDEG + r3] = s.w;
    else { int o = atomicAdd(ovfCnt, 1); if (o < OVF_CAP) ovf[o] = make_int2(s.w, d.w); }
}

// Phase 2: one wave per node; 16-lane subgroups x float4; 8 edges in flight (2-deep unroll).
__global__ __launch_bounds__(256) void gather_sum_wave(
    const float* __restrict__ x, const int* __restrict__ slots,
    const int* __restrict__ count, float* __restrict__ out)
{
    const int lane = threadIdx.x & 63;
    const int node = blockIdx.x * 4 + (threadIdx.x >> 6);
    if (node >= N_NODES) return;
    const int equad = lane >> 4;    // edge subgroup 0..3
    const int quad  = lane & 15;    // float4 index within the 64-feat row

    const int cnt  = min(count[node], MAXDEG);
    const int base = node * MAXDEG;

    float4 a0 = {0.f, 0.f, 0.f, 0.f};
    float4 a1 = {0.f, 0.f, 0.f, 0.f};
    const float4* __restrict__ x4 = (const float4*)x;   // row = 16 float4s

    int i = equad;
    for (; i + 4 < cnt; i += 8) {
        int s0 = slots[base + i];
        int s1 = slots[base + i + 4];
        float4 v0 = x4[(size_t)s0 * 16 + quad];
        float4 v1 = x4[(size_t)s1 * 16 + quad];
        a0.x += v0.x; a0.y += v0.y; a0.z += v0.z; a0.w += v0.w;
        a1.x += v1.x; a1.y += v1.y; a1.z += v1.z; a1.w += v1.w;
    }
    if (i < cnt) {
        int s0 = slots[base + i];
        float4 v0 = x4[(size_t)s0 * 16 + quad];
        a0.x += v0.x; a0.y += v0.y; a0.z += v0.z; a0.w += v0.w;
    }

    a0.x += a1.x; a0.y += a1.y; a0.z += a1.z; a0.w += a1.w;
    // reduce the 4 edge-subgroups: lane l <-> l^16, then l^32
    a0.x += __shfl_xor(a0.x, 16, 64); a0.y += __shfl_xor(a0.y, 16, 64);
    a0.z += __shfl_xor(a0.z, 16, 64); a0.w += __shfl_xor(a0.w, 16, 64);
    a0.x += __shfl_xor(a0.x, 32, 64); a0.y += __shfl_xor(a0.y, 32, 64);
    a0.z += __shfl_xor(a0.z, 32, 64); a0.w += __shfl_xor(a0.w, 32, 64);

    if (lane < 16) ((float4*)out)[(size_t)node * 16 + quad] = a0;
}

// Phase 3: add the (normally zero) overflow edges on top of out.
__global__ __launch_bounds__(256) void ovf_fixup(
    const float* __restrict__ x, const int2* __restrict__ ovf,
    const int* __restrict__ ovfCnt, float* __restrict__ out)
{
    const int n = min(*ovfCnt, OVF_CAP);
    const int wave = (blockIdx.x * blockDim.x + threadIdx.x) >> 6;
    const int lane = threadIdx.x & 63;
    const int nwaves = (gridDim.x * blockDim.x) >> 6;
    for (int e = wave; e < n; e += nwaves) {
        int2 p = ovf[e];   // (src, dst)
        atomicAdd(&out[(size_t)p.y * D_FEAT + lane], x[(size_t)p.x * D_FEAT + lane]);
    }
}

extern "C" void kernel_launch(void* const* d_in, const int* in_sizes, int n_in,
                              void* d_out, int out_size, void* d_ws, size_t ws_size,
                              hipStream_t stream) {
    const float* x = (const float*)d_in[0];
    const int* edge_index = (const int*)d_in[1];    // [2, N_EDGES] flat int32
    const int* src = edge_index;
    const int* dst = edge_index + N_EDGES;
    float* out = (float*)d_out;

    // Workspace (ints): count[N] | ovfCnt | pad | ovf[2*OVF_CAP] | slots[N*MAXDEG]
    int*  count  = (int*)d_ws;
    int*  ovfCnt = count + N_NODES;
    int2* ovf    = (int2*)(count + N_NODES + 2);    // 8B-aligned (N_NODES even)
    int*  slots  = (int*)(ovf + OVF_CAP);

    // zero count + ovfCnt (+pad) in one memset
    hipMemsetAsync(count, 0, (size_t)(N_NODES + 2) * sizeof(int), stream);

    const int eb = 256;
    const int eg4 = (E4 + eb - 1) / eb;
    histo_scatter4<<<eg4, eb, 0, stream>>>(src, dst, count, slots, ovfCnt, ovf);

    gather_sum_wave<<<(N_NODES + 3) / 4, 256, 0, stream>>>(x, slots, count, out);

    ovf_fixup<<<16, 256, 0, stream>>>(x, ovf, ovfCnt, out);
}